// Round 8
// baseline (237.269 us; speedup 1.0000x reference)
//
#include <hip/hip_runtime.h>

#define N_PTS 150000
#define NK 27
#define CIN 128
#define COUT 128
#define BM 256
#define NBLK ((N_PTS + BM - 1) / BM)   // 586

typedef __attribute__((ext_vector_type(8))) short bfrag8;   // 8 bf16
typedef __attribute__((ext_vector_type(4))) float facc4;    // 4 f32

__device__ inline unsigned short f2bf(float f) {
    unsigned u = __builtin_bit_cast(unsigned, f);
    u += 0x7FFFu + ((u >> 16) & 1u);            // RNE
    return (unsigned short)(u >> 16);
}
__device__ inline unsigned pack2(float a, float b) {
    return (unsigned)f2bf(a) | ((unsigned)f2bf(b) << 16);
}
__device__ inline void glds16(const void* g, void* l) {
    __builtin_amdgcn_global_load_lds(
        (const __attribute__((address_space(1))) void*)g,
        (__attribute__((address_space(3))) void*)l, 16, 0, 0);
}
// one barrier per phase: drains B-glds (LDS writes live in vmcnt domain)
__device__ inline void phase_barrier() {
    __builtin_amdgcn_sched_barrier(0);
    asm volatile("s_waitcnt vmcnt(0)" ::: "memory");
    __builtin_amdgcn_s_barrier();
    __builtin_amdgcn_sched_barrier(0);
}

// ---- prep: fp32 data -> bf16, plus one zeroed row at index N_PTS ----
__global__ void cast_data_kernel(const float* __restrict__ in,
                                 unsigned short* __restrict__ out) {
    const int n8_data = N_PTS * (CIN / 8);
    const int n8_all  = (N_PTS + 1) * (CIN / 8);
    int i = blockIdx.x * blockDim.x + threadIdx.x;
    int stride = gridDim.x * blockDim.x;
    for (; i < n8_all; i += stride) {
        uint4 v;
        if (i < n8_data) {
            const float4* p = (const float4*)(in + (size_t)i * 8);
            float4 x = p[0], y = p[1];
            v.x = pack2(x.x, x.y); v.y = pack2(x.z, x.w);
            v.z = pack2(y.x, y.y); v.w = pack2(y.z, y.w);
        } else {
            v.x = v.y = v.z = v.w = 0u;
        }
        *(uint4*)(out + (size_t)i * 8) = v;
    }
}

// ---- prep: W[co][k][ci] -> wkh[k][h][co][bu] bf16 16B units, pre-swizzled bu^(co&7) ----
__global__ void prep_weights_h(const float* __restrict__ w,
                               unsigned short* __restrict__ wkh) {
    int i = blockIdx.x * blockDim.x + threadIdx.x;
    if (i >= NK * 2 * 128 * 8) return;
    int bu = i & 7, co = (i >> 3) & 127, h = (i >> 10) & 1, k = i >> 11;
    int ci = h * 64 + (bu ^ (co & 7)) * 8;
    const float4* src = (const float4*)(w + ((size_t)co * NK + k) * CIN + ci);
    float4 x = src[0], y = src[1];
    uint4 v;
    v.x = pack2(x.x, x.y); v.y = pack2(x.z, x.w);
    v.z = pack2(y.x, y.y); v.w = pack2(y.z, y.w);
    ((uint4*)wkh)[i] = v;
}

// ================= main kernel (v7) =================
// 512 threads / 8 waves, BM=256, wave = 32 rows x FULL 128 couts.
// A: gather DIRECT to registers (each row owned by exactly one wave -> no
//    duplication, no A-LDS, no A staging barrier). 1-deep double set SX/SY.
// B: 2x16KB LDS dbuf via linear glds16 from pre-swizzled wkh (rule #21).
// idx: LDS slab. One vmcnt(0) barrier per phase; LDS = 59.6KB -> 2 blocks/CU.

#define ISSUE_A(SET, IV, HB)                                                 \
  {                                                                          \
    size_t e0_ = (r0ok && (IV).x >= 0) ? (size_t)(IV).x : (size_t)N_PTS;     \
    size_t e1_ = (r1ok && (IV).y >= 0) ? (size_t)(IV).y : (size_t)N_PTS;     \
    const char* p0_ = dbfB + e0_ * 256 + (HB) + lk * 16;                     \
    const char* p1_ = dbfB + e1_ * 256 + (HB) + lk * 16;                     \
    SET##00 = *(const uint4*)(p0_);                                          \
    SET##01 = *(const uint4*)(p0_ + 64);                                     \
    SET##10 = *(const uint4*)(p1_);                                          \
    SET##11 = *(const uint4*)(p1_ + 64);                                     \
  }

#define STAGE_B(Q, BBUF)                                                     \
  {                                                                          \
    const char* bs_ = wkhB + (size_t)(Q) * 16384 + w * 2048 + l * 16;        \
    glds16(bs_,        (BBUF) + w * 2048 + l * 16);                          \
    glds16(bs_ + 1024, (BBUF) + w * 2048 + 1024 + l * 16);                   \
  }

#define MFMA_PHASE(SET, BBUF)                                                        \
  {                                                                                  \
    __builtin_amdgcn_s_setprio(1);                                                   \
    _Pragma("unroll")                                                                \
    for (int ct = 0; ct < 8; ++ct) {                                                 \
      const int bro_ = (ct * 16 + lr) * 128;                                         \
      bfrag8 b0 = *(const bfrag8*)((BBUF) + bro_ + ((lk ^ (lr & 7)) << 4));          \
      bfrag8 b1 = *(const bfrag8*)((BBUF) + bro_ + (((4 + lk) ^ (lr & 7)) << 4));    \
      acc[0][ct] = __builtin_amdgcn_mfma_f32_16x16x32_bf16(                          \
          __builtin_bit_cast(bfrag8, SET##00), b0, acc[0][ct], 0, 0, 0);             \
      acc[1][ct] = __builtin_amdgcn_mfma_f32_16x16x32_bf16(                          \
          __builtin_bit_cast(bfrag8, SET##10), b0, acc[1][ct], 0, 0, 0);             \
      acc[0][ct] = __builtin_amdgcn_mfma_f32_16x16x32_bf16(                          \
          __builtin_bit_cast(bfrag8, SET##01), b1, acc[0][ct], 0, 0, 0);             \
      acc[1][ct] = __builtin_amdgcn_mfma_f32_16x16x32_bf16(                          \
          __builtin_bit_cast(bfrag8, SET##11), b1, acc[1][ct], 0, 0, 0);             \
    }                                                                                \
    __builtin_amdgcn_s_setprio(0);                                                   \
  }

__global__ __launch_bounds__(512, 4)
void octconv_v7(const unsigned short* __restrict__ dbf,   // [N_PTS+1][128] bf16
                const unsigned short* __restrict__ wkh,   // [27][2][128][8u] preswz
                const int* __restrict__ nbr,
                float* __restrict__ out) {
    __shared__ __align__(1024) unsigned char lds[32768 + 27648];  // B dbuf 32K | idx 27K

    const int t = threadIdx.x;
    const int w = t >> 6, l = t & 63;
    const int lr = l & 15, lk = l >> 4;
    const int m0 = blockIdx.x * BM;

    const int row0 = m0 + w * 32 + lr;          // rt=0 row for this lane
    const bool r0ok = row0 < N_PTS;
    const bool r1ok = (row0 + 16) < N_PTS;

    const char* dbfB = (const char*)dbf;
    const char* wkhB = (const char*)wkh;
    char* ldsB0 = (char*)lds;
    char* ldsB1 = (char*)lds + 16384;
    char* ldsI  = (char*)lds + 32768;

    const int islab0 = (w * 32 + lr) * 108;
    const int islab1 = (w * 32 + 16 + lr) * 108;

    facc4 acc[2][8];
    const facc4 fz = {0.f, 0.f, 0.f, 0.f};
#pragma unroll
    for (int a = 0; a < 2; ++a)
#pragma unroll
        for (int b = 0; b < 8; ++b) acc[a][b] = fz;

    // ---- prologue: idx slab (guarded at tail) + B(0) ----
    {
        const char* nsrc = (const char*)nbr + (size_t)m0 * 108;
        const int rows_valid = (N_PTS - m0) < BM ? (N_PTS - m0) : BM;
        const int nlimit = rows_valid * 108;
        int o;
        o = t * 16;         if (o < nlimit) glds16(nsrc + o, ldsI + o);
        o = 8192 + t * 16;  if (o < nlimit) glds16(nsrc + o, ldsI + o);
        o = 16384 + t * 16; if (o < nlimit) glds16(nsrc + o, ldsI + o);
        o = 24576 + t * 16; if (t < 192 && o < nlimit) glds16(nsrc + o, ldsI + o);
        STAGE_B(0, ldsB0)
    }
    phase_barrier();

    int2 ivC, ivN;
    ivC.x = *(const int*)(ldsI + islab0);
    ivC.y = *(const int*)(ldsI + islab1);

    uint4 sx00, sx01, sx10, sx11;   // even-phase A set
    uint4 sy00, sy01, sy10, sy11;   // odd-phase A set
    ISSUE_A(sx, ivC, 0)             // (k=0, h=0)

#pragma unroll 1
    for (int k = 0; k < NK; ++k) {
        // even phase p=2k: compute (k,h=0) from buf0; stage B(2k+1)->buf1;
        // prefetch idx(k+1); issue SY = A(k, h=1)
        STAGE_B(2 * k + 1, ldsB1)
        {
            const int kn = (k + 1 < NK) ? k + 1 : NK - 1;
            ivN.x = *(const int*)(ldsI + islab0 + kn * 4);
            ivN.y = *(const int*)(ldsI + islab1 + kn * 4);
        }
        ISSUE_A(sy, ivC, 128)
        MFMA_PHASE(sx, ldsB0)
        phase_barrier();
        // odd phase p=2k+1: compute (k,h=1) from buf1; stage B(2k+2)->buf0;
        // issue SX = A(k+1, h=0)
        if (k + 1 < NK) {
            STAGE_B(2 * k + 2, ldsB0)
            ISSUE_A(sx, ivN, 0)
        }
        MFMA_PHASE(sy, ldsB1)
        if (k + 1 < NK) phase_barrier();
        ivC = ivN;
    }

    // ---- epilogue: C/D col=lane&15, row=(lane>>4)*4+reg ----
#pragma unroll
    for (int rt = 0; rt < 2; ++rt) {
        const int r0 = m0 + w * 32 + rt * 16 + lk * 4;
#pragma unroll
        for (int ct = 0; ct < 8; ++ct) {
#pragma unroll
            for (int r = 0; r < 4; ++r) {
                int row = r0 + r;
                if (row < N_PTS)
                    out[(size_t)row * COUT + ct * 16 + lr] = acc[rt][ct][r];
            }
        }
    }
}

// ---- emergency fallback ----
__global__ void naive_kernel(const float* __restrict__ data, const float* __restrict__ wgt,
                             const int* __restrict__ nbr, float* __restrict__ out) {
    int mm = blockIdx.x;
    int co = threadIdx.x;
    if (mm >= N_PTS) return;
    float acc = 0.f;
    for (int k = 0; k < NK; ++k) {
        int idx = nbr[mm * NK + k];
        if (idx < 0) continue;
        const float* d  = data + (size_t)idx * CIN;
        const float* wp = wgt + ((size_t)co * NK + k) * CIN;
        for (int ci = 0; ci < CIN; ++ci) acc += d[ci] * wp[ci];
    }
    out[(size_t)mm * COUT + co] = acc;
}

extern "C" void kernel_launch(void* const* d_in, const int* in_sizes, int n_in,
                              void* d_out, int out_size, void* d_ws, size_t ws_size,
                              hipStream_t stream) {
    const float* data = (const float*)d_in[0];
    const float* wgt  = (const float*)d_in[1];
    const int*   nbr  = (const int*)d_in[2];
    float*       out  = (float*)d_out;

    const size_t wk_bytes  = (size_t)NK * 2 * 128 * 8 * 16;    // 884,736
    const size_t dbf_bytes = (size_t)(N_PTS + 1) * CIN * 2;    // 38,400,256

    if (ws_size < wk_bytes + dbf_bytes) {
        naive_kernel<<<N_PTS, COUT, 0, stream>>>(data, wgt, nbr, out);
        return;
    }
    unsigned short* wkh = (unsigned short*)d_ws;
    unsigned short* dbf = (unsigned short*)((char*)d_ws + wk_bytes);

    prep_weights_h<<<(NK * 2 * 128 * 8 + 255) / 256, 256, 0, stream>>>(wgt, wkh);
    cast_data_kernel<<<2048, 256, 0, stream>>>(data, dbf);

    octconv_v7<<<NBLK, 512, 0, stream>>>(dbf, wkh, nbr, out);
}

// Round 9
// 197.190 us; speedup vs baseline: 1.2032x; 1.2032x over previous
//
#include <hip/hip_runtime.h>

#define N_PTS 150000
#define NK 27
#define CIN 128
#define COUT 128
#define BM 256
#define NBLK ((N_PTS + BM - 1) / BM)   // 586

typedef __attribute__((ext_vector_type(8))) short bfrag8;   // 8 bf16
typedef __attribute__((ext_vector_type(4))) float facc4;    // 4 f32

__device__ inline unsigned short f2bf(float f) {
    unsigned u = __builtin_bit_cast(unsigned, f);
    u += 0x7FFFu + ((u >> 16) & 1u);            // RNE
    return (unsigned short)(u >> 16);
}
__device__ inline unsigned pack2(float a, float b) {
    return (unsigned)f2bf(a) | ((unsigned)f2bf(b) << 16);
}
__device__ inline void glds16(const void* g, void* l) {
    __builtin_amdgcn_global_load_lds(
        (const __attribute__((address_space(1))) void*)g,
        (__attribute__((address_space(3))) void*)l, 16, 0, 0);
}

// ---- prep: fp32 data -> bf16, plus one zeroed row at index N_PTS ----
__global__ void cast_data_kernel(const float* __restrict__ in,
                                 unsigned short* __restrict__ out) {
    const int n8_data = N_PTS * (CIN / 8);
    const int n8_all  = (N_PTS + 1) * (CIN / 8);
    int i = blockIdx.x * blockDim.x + threadIdx.x;
    int stride = gridDim.x * blockDim.x;
    for (; i < n8_all; i += stride) {
        uint4 v;
        if (i < n8_data) {
            const float4* p = (const float4*)(in + (size_t)i * 8);
            float4 x = p[0], y = p[1];
            v.x = pack2(x.x, x.y); v.y = pack2(x.z, x.w);
            v.z = pack2(y.x, y.y); v.w = pack2(y.z, y.w);
        } else {
            v.x = v.y = v.z = v.w = 0u;
        }
        *(uint4*)(out + (size_t)i * 8) = v;
    }
}

// ---- prep: W[co][k][ci] -> wkh[k][h][co][bu] bf16 16B units, pre-swizzled bu^(co&7) ----
__global__ void prep_weights_h(const float* __restrict__ w,
                               unsigned short* __restrict__ wkh) {
    int i = blockIdx.x * blockDim.x + threadIdx.x;
    if (i >= NK * 2 * 128 * 8) return;
    int bu = i & 7, co = (i >> 3) & 127, h = (i >> 10) & 1, k = i >> 11;
    int ci = h * 64 + (bu ^ (co & 7)) * 8;
    const float4* src = (const float4*)(w + ((size_t)co * NK + k) * CIN + ci);
    float4 x = src[0], y = src[1];
    uint4 v;
    v.x = pack2(x.x, x.y); v.y = pack2(x.z, x.w);
    v.z = pack2(y.x, y.y); v.w = pack2(y.z, y.w);
    ((uint4*)wkh)[i] = v;
}

// ================= main kernel (v8 = v5 + T4 counted vmcnt) =================
// 1024 threads / 16 waves, BM=256, wave = 32 rows x 64 couts, 54 phases (K=64).
// A: glds gather, TRIPLE buffer (3x32KB), staged 2 phases ahead.
// B: glds, double buffer (2x16KB), staged 1 phase ahead, issued BEFORE A.
// idx: LDS slab. Loop vmem = exactly 3 glds/thread/phase (B1 then A2), so
// end-of-phase s_waitcnt vmcnt(2) leaves exactly the next A-tile in flight.
// Queue (per wave): enter p: [A(p+1)x2] -> +B(p+1) +A(p+2)x2 -> vmcnt(2)
// completes A(p+1),B(p+1), leaves A(p+2). LDS 158.7KB -> 1 block/CU.

#define STAGE_A(Q, ADST)                                                     \
  {                                                                          \
    const int q_ = (Q);                                                      \
    const int k_ = q_ >> 1;                                                  \
    const int hb_ = (q_ & 1) << 7;                                           \
    int iv0 = *(const int*)(ldsI + i0base + k_ * 4);                         \
    int iv1 = *(const int*)(ldsI + i1base + k_ * 4);                         \
    size_t e0 = (r0ok && iv0 >= 0) ? (size_t)iv0 : (size_t)N_PTS;            \
    size_t e1 = (r1ok && iv1 >= 0) ? (size_t)iv1 : (size_t)N_PTS;            \
    glds16(dbfB + e0 * 256 + hb_ + aswz0, (ADST) + adst0);                   \
    glds16(dbfB + e1 * 256 + hb_ + aswz1, (ADST) + adst1);                   \
  }

#define STAGE_B(Q, BDST)                                                     \
    glds16(wkhB + (size_t)(Q) * 16384 + bsrc_c, (BDST) + bdst_lin);

#define MFMA_PHASE(ABUF, BBUF)                                                      \
  {                                                                                 \
    __builtin_amdgcn_s_setprio(1);                                                  \
    _Pragma("unroll")                                                               \
    for (int kk = 0; kk < 2; ++kk) {                                                \
      const int sw_ = (((kk * 4 + lk) ^ (lr & 7)) << 4);                            \
      bfrag8 a0 = *(const bfrag8*)((ABUF) + (wrow * 32 + lr) * 128 + sw_);          \
      bfrag8 a1 = *(const bfrag8*)((ABUF) + (wrow * 32 + 16 + lr) * 128 + sw_);     \
      _Pragma("unroll")                                                             \
      for (int ct = 0; ct < 4; ++ct) {                                              \
        bfrag8 b = *(const bfrag8*)((BBUF) + (h * 64 + ct * 16 + lr) * 128 + sw_);  \
        acc[0][ct] = __builtin_amdgcn_mfma_f32_16x16x32_bf16(a0, b, acc[0][ct],     \
                                                             0, 0, 0);              \
        acc[1][ct] = __builtin_amdgcn_mfma_f32_16x16x32_bf16(a1, b, acc[1][ct],     \
                                                             0, 0, 0);              \
      }                                                                             \
    }                                                                               \
    __builtin_amdgcn_s_setprio(0);                                                  \
  }

#define WAIT_BAR(N)                                                          \
    __builtin_amdgcn_sched_barrier(0);                                       \
    asm volatile("s_waitcnt vmcnt(" #N ")" ::: "memory");                    \
    __builtin_amdgcn_s_barrier();                                            \
    __builtin_amdgcn_sched_barrier(0);

__global__ __launch_bounds__(1024, 4)
void octconv_v8(const unsigned short* __restrict__ dbf,   // [N_PTS+1][128] bf16
                const unsigned short* __restrict__ wkh,   // [27][2][128][8u] preswz
                const int* __restrict__ nbr,
                float* __restrict__ out) {
    // A triple 96K | B double 32K | idx 27K = 158720 B
    __shared__ __align__(1024) unsigned char lds[3 * 32768 + 2 * 16384 + 27648];

    const int t = threadIdx.x;
    const int w = t >> 6, l = t & 63;
    const int lr = l & 15, lk = l >> 4;
    const int h = w & 1, wrow = w >> 1;
    const int m0 = blockIdx.x * BM;

    const int lu    = l & 7;
    const int slot0 = w * 16 + (l >> 3);
    const int slot1 = slot0 + 8;
    const bool r0ok = (m0 + slot0) < N_PTS;
    const bool r1ok = (m0 + slot1) < N_PTS;
    const int aswz0 = (lu ^ (slot0 & 7)) << 4;
    const int aswz1 = (lu ^ (slot1 & 7)) << 4;
    const int adst0 = slot0 * 128 + lu * 16;     // linear LDS dest (rule #21)
    const int adst1 = slot1 * 128 + lu * 16;
    const int bsrc_c = t * 16;                   // linear: wkh pre-swizzled
    const int bdst_lin = t * 16;
    const int i0base = slot0 * 108;
    const int i1base = slot1 * 108;

    const char* dbfB = (const char*)dbf;
    const char* wkhB = (const char*)wkh;
    char* a0p = (char*)lds;                      // A buf for phase p
    char* a1p = (char*)lds + 32768;              // phase p+1
    char* a2p = (char*)lds + 65536;              // phase p+2 (write target)
    char* b0p = (char*)lds + 98304;              // B buf for phase p
    char* b1p = (char*)lds + 114688;             // phase p+1 (write target)
    char* ldsI = (char*)lds + 131072;

    facc4 acc[2][4];
    const facc4 fz = {0.f, 0.f, 0.f, 0.f};
#pragma unroll
    for (int a = 0; a < 2; ++a)
#pragma unroll
        for (int b = 0; b < 4; ++b) acc[a][b] = fz;

    // ---- prologue 1: idx slab via glds (guarded at tail block) ----
    {
        const char* nsrc = (const char*)nbr + (size_t)m0 * 108;
        const int rows_valid = (N_PTS - m0) < BM ? (N_PTS - m0) : BM;
        const int nlimit = rows_valid * 108;
        int o1 = t * 16;
        if (o1 < nlimit) glds16(nsrc + o1, ldsI + o1);
        int o2 = 16384 + t * 16;
        if (t < 704 && o2 < nlimit) glds16(nsrc + o2, ldsI + o2);
    }
    WAIT_BAR(0)

    // ---- prologue 2: A(0),B(0),A(1),B(1) -> wait 3 (A0+B0 done) ----
    STAGE_A(0, a0p)
    STAGE_B(0, b0p)
    STAGE_A(1, a1p)
    STAGE_B(1, b1p)
    WAIT_BAR(3)

    // ---- phase 0: stage A(2); compute 0; A(1),B(1) drain ----
    STAGE_A(2, a2p)
    MFMA_PHASE(a0p, b0p)
    WAIT_BAR(2)
    { char* tp = a0p; a0p = a1p; a1p = a2p; a2p = tp; }
    { char* tp = b0p; b0p = b1p; b1p = tp; }

    // ---- phases 1..51: uniform {B(p+1); A(p+2); MFMA(p); vmcnt(2)} ----
#pragma unroll 1
    for (int p = 1; p <= 51; ++p) {
        STAGE_B(p + 1, b1p)
        STAGE_A(p + 2, a2p)
        MFMA_PHASE(a0p, b0p)
        WAIT_BAR(2)
        { char* tp = a0p; a0p = a1p; a1p = a2p; a2p = tp; }
        { char* tp = b0p; b0p = b1p; b1p = tp; }
    }

    // ---- phase 52: stage B(53); compute 52; drain all ----
    STAGE_B(53, b1p)
    MFMA_PHASE(a0p, b0p)
    WAIT_BAR(0)
    { char* tp = a0p; a0p = a1p; a1p = a2p; a2p = tp; }
    { char* tp = b0p; b0p = b1p; b1p = tp; }

    // ---- phase 53: compute only ----
    MFMA_PHASE(a0p, b0p)

    // ---- epilogue: C/D col=lane&15, row=(lane>>4)*4+reg ----
#pragma unroll
    for (int rt = 0; rt < 2; ++rt) {
        const int r0 = m0 + wrow * 32 + rt * 16 + lk * 4;
#pragma unroll
        for (int ct = 0; ct < 4; ++ct) {
#pragma unroll
            for (int r = 0; r < 4; ++r) {
                int row = r0 + r;
                if (row < N_PTS)
                    out[(size_t)row * COUT + h * 64 + ct * 16 + lr] = acc[rt][ct][r];
            }
        }
    }
}

// ---- emergency fallback ----
__global__ void naive_kernel(const float* __restrict__ data, const float* __restrict__ wgt,
                             const int* __restrict__ nbr, float* __restrict__ out) {
    int mm = blockIdx.x;
    int co = threadIdx.x;
    if (mm >= N_PTS) return;
    float acc = 0.f;
    for (int k = 0; k < NK; ++k) {
        int idx = nbr[mm * NK + k];
        if (idx < 0) continue;
        const float* d  = data + (size_t)idx * CIN;
        const float* wp = wgt + ((size_t)co * NK + k) * CIN;
        for (int ci = 0; ci < CIN; ++ci) acc += d[ci] * wp[ci];
    }
    out[(size_t)mm * COUT + co] = acc;
}

extern "C" void kernel_launch(void* const* d_in, const int* in_sizes, int n_in,
                              void* d_out, int out_size, void* d_ws, size_t ws_size,
                              hipStream_t stream) {
    const float* data = (const float*)d_in[0];
    const float* wgt  = (const float*)d_in[1];
    const int*   nbr  = (const int*)d_in[2];
    float*       out  = (float*)d_out;

    const size_t wk_bytes  = (size_t)NK * 2 * 128 * 8 * 16;    // 884,736
    const size_t dbf_bytes = (size_t)(N_PTS + 1) * CIN * 2;    // 38,400,256

    if (ws_size < wk_bytes + dbf_bytes) {
        naive_kernel<<<N_PTS, COUT, 0, stream>>>(data, wgt, nbr, out);
        return;
    }
    unsigned short* wkh = (unsigned short*)d_ws;
    unsigned short* dbf = (unsigned short*)((char*)d_ws + wk_bytes);

    prep_weights_h<<<(NK * 2 * 128 * 8 + 255) / 256, 256, 0, stream>>>(wgt, wkh);
    cast_data_kernel<<<2048, 256, 0, stream>>>(data, dbf);

    octconv_v8<<<NBLK, 1024, 0, stream>>>(dbf, wkh, nbr, out);
}